// Round 10
// baseline (4556.652 us; speedup 1.0000x reference)
//
#include <hip/hip_runtime.h>
#include <hip/hip_bf16.h>
#include <hip/hip_fp16.h>

using half2_t = __attribute__((ext_vector_type(2))) _Float16;
using half8_t = __attribute__((ext_vector_type(8))) _Float16;
using f32x4   = __attribute__((ext_vector_type(4))) float;
using i32x4   = __attribute__((ext_vector_type(4))) int;

#define B_   64
#define T_   2048
#define D_   256
#define U_   256
#define NG   768
#define TC   512
#define NCHUNK (T_/TC)
#define GB_SCAN 32     // scan blocks (2 batches each, 8 active waves)
#define GB_GEMM 1536
#define GB_LN   2048

typedef const __attribute__((address_space(1))) void* gptr_t;
typedef __attribute__((address_space(3))) void* lptr_t;

__device__ __forceinline__ float rcpf(float x) { return __builtin_amdgcn_rcpf(x); }

// ---------------- prep kernels ----------------

__global__ void conv_x_chunk(const float* __restrict__ x, _Float16* __restrict__ xh, int t0) {
  size_t idx = ((size_t)blockIdx.x * 256 + threadIdx.x) * 8;
  int b   = (int)(idx >> 17);
  int rem = (int)(idx & 131071);
  const float4* p = (const float4*)(x + ((size_t)(b * T_ + t0)) * D_ + rem);
  float4 v0 = p[0], v1 = p[1];
  half8_t o;
  o[0] = (_Float16)v0.x; o[1] = (_Float16)v0.y; o[2] = (_Float16)v0.z; o[3] = (_Float16)v0.w;
  o[4] = (_Float16)v1.x; o[5] = (_Float16)v1.y; o[6] = (_Float16)v1.z; o[7] = (_Float16)v1.w;
  *(half8_t*)(xh + idx) = o;
}

__global__ void conv_T(const float* __restrict__ src, _Float16* __restrict__ dst) {
  int idx = blockIdx.x * 256 + threadIdx.x;
  int d = idx / NG;
  int j = idx - d * NG;
  dst[j * 256 + d] = (_Float16)src[idx];
}

__global__ void init_scale(unsigned* s) { if (threadIdx.x == 0) *s = 0u; }

__global__ void absmax_rec(const float* __restrict__ rec, unsigned* __restrict__ s) {
  int i = (blockIdx.x * 256 + threadIdx.x) * 4;
  float4 v = *(const float4*)(rec + i);
  float m = fmaxf(fmaxf(fabsf(v.x), fabsf(v.y)), fmaxf(fabsf(v.z), fabsf(v.w)));
  #pragma unroll
  for (int off = 32; off >= 1; off >>= 1) m = fmaxf(m, __shfl_xor(m, off));
  __shared__ float sm[4];
  int l = threadIdx.x & 63, wv = threadIdx.x >> 6;
  if (l == 0) sm[wv] = m;
  __syncthreads();
  if (threadIdx.x == 0) {
    m = fmaxf(fmaxf(sm[0], sm[1]), fmaxf(sm[2], sm[3]));
    atomicMax(s, __float_as_uint(m));
  }
}

// rec [256][768] f32 -> i8 A-fragment layout [48 mt][4 ks][64 lane][16B]
__global__ void conv_rec_i8(const float* __restrict__ rec, const unsigned* __restrict__ sc,
                            char* __restrict__ dst) {
  int idx = blockIdx.x * 256 + threadIdx.x;
  int j = idx & 15, l = (idx >> 4) & 63, sl = idx >> 10;
  int mt = sl >> 2, ks = sl & 3, bi = l & 15, hi = l >> 4;
  float am = __uint_as_float(*sc) + 1e-30f;
  float s = 127.f / am;
  float v = rec[(size_t)(ks * 64 + hi * 16 + j) * NG + mt * 16 + bi] * s;
  int q = __float2int_rn(v);
  q = q > 127 ? 127 : (q < -127 ? -127 : q);
  dst[idx] = (char)q;
}

// ---------------- mega kernel: [scan | gemm | ln] by blockIdx range ----------------
// xws page per (g,t): 1536 f16 = 3072 B: [0,2048)B zr u32 by stid; [2048,3072)B h-gate f16 by stid

__global__ __launch_bounds__(1024) void mega(
    const char* __restrict__ rq,        // [48][4][64][16] i8
    const _Float16* __restrict__ xwsS,
    const unsigned* __restrict__ sc,
    float* __restrict__ out,
    float* __restrict__ hg,
    int scanT0,
    const _Float16* __restrict__ xhc,
    const _Float16* __restrict__ kT,
    const float* __restrict__ bias,
    _Float16* __restrict__ xwsG,
    const float* __restrict__ gamma,
    const float* __restrict__ beta,
    int lnT0,
    int nScan, int nGemm)
{
  __shared__ union UU {
    struct { alignas(16) char Hq[2][512]; } s;
    struct { alignas(16) _Float16 As[128 * 32]; alignas(16) _Float16 Bs[128 * 32]; } g;
  } U;

  int bid = blockIdx.x;
  const int tid = threadIdx.x;

  // ================= SCAN (32 blocks, 2 batches each; waves 0-7 active) =================
  if (bid < nScan) {
    const int g = bid;
    const int w = tid >> 6, l = tid & 63, bi = l & 15, hi = l >> 4;
    if (w < 8) {
      const int bc = bi & 1;
      const int sq = bi >> 1;            // [0,8)
      const int s2 = sq >> 2, qq = sq & 3;
      const int u = 32 * w + s2 * 16 + hi * 4 + qq;

      // 24 A-frags, pinned to AGPRs
      const i32x4* rp = (const i32x4*)rq;
#define FR(mt, ks) rp[((mt) * 4 + (ks)) * 64 + l]
      i32x4 Z00 = FR(2*w, 0),    Z01 = FR(2*w, 1),    Z02 = FR(2*w, 2),    Z03 = FR(2*w, 3);
      i32x4 Z10 = FR(2*w+1, 0),  Z11 = FR(2*w+1, 1),  Z12 = FR(2*w+1, 2),  Z13 = FR(2*w+1, 3);
      i32x4 R00 = FR(16+2*w, 0), R01 = FR(16+2*w, 1), R02 = FR(16+2*w, 2), R03 = FR(16+2*w, 3);
      i32x4 R10 = FR(17+2*w, 0), R11 = FR(17+2*w, 1), R12 = FR(17+2*w, 2), R13 = FR(17+2*w, 3);
      i32x4 H00 = FR(32+2*w, 0), H01 = FR(32+2*w, 1), H02 = FR(32+2*w, 2), H03 = FR(32+2*w, 3);
      i32x4 H10 = FR(33+2*w, 0), H11 = FR(33+2*w, 1), H12 = FR(33+2*w, 2), H13 = FR(33+2*w, 3);
#undef FR
      asm volatile("" : "+a"(Z00), "+a"(Z01), "+a"(Z02), "+a"(Z03),
                        "+a"(Z10), "+a"(Z11), "+a"(Z12), "+a"(Z13));
      asm volatile("" : "+a"(R00), "+a"(R01), "+a"(R02), "+a"(R03),
                        "+a"(R10), "+a"(R11), "+a"(R12), "+a"(R13));
      asm volatile("" : "+a"(H00), "+a"(H01), "+a"(H02), "+a"(H03),
                        "+a"(H10), "+a"(H11), "+a"(H12), "+a"(H13));

      const float dq = (__uint_as_float(*sc) + 1e-30f) / (127.f * 127.f);

      float h = (scanT0 == 0) ? 0.f : hg[(size_t)(g * 2 + bc) * 256 + u];

      const int hwa = bc * 256 + u;
      { int q8 = __float2int_rn(h * 127.f); U.s.Hq[0][hwa] = (char)q8; }

      const char* xpg = (const char*)xwsS + (size_t)g * TC * 3072;
      float* outp = out + ((size_t)(g * 2 + bc) * T_ + scanT0) * U_ + u;

      unsigned nzr = *(const unsigned*)(xpg + tid * 4);
      _Float16 nh2 = *(const _Float16*)(xpg + 2048 + tid * 2);
      __syncthreads();

      for (int t = 0; t < TC; ++t) {
        half2_t zrp = __builtin_bit_cast(half2_t, nzr);
        float xzf = (float)zrp[0], xrf = (float)zrp[1], xhf = (float)nh2;
        {
          int tn = (t + 1 < TC) ? (t + 1) : t;
          nzr = *(const unsigned*)(xpg + (size_t)tn * 3072 + tid * 4);
          nh2 = *(const _Float16*)(xpg + (size_t)tn * 3072 + 2048 + tid * 2);
        }

        const char* hb = &U.s.Hq[t & 1][0];
        i32x4 az0 = {}, az1 = {}, ar0 = {}, ar1 = {}, ah0 = {}, ah1 = {};
        { i32x4 Bf;
          Bf = *(const i32x4*)(hb + bc * 256 + 0 * 64 + hi * 16);
          az0 = __builtin_amdgcn_mfma_i32_16x16x64_i8(Z00, Bf, az0, 0, 0, 0);
          az1 = __builtin_amdgcn_mfma_i32_16x16x64_i8(Z10, Bf, az1, 0, 0, 0);
          ar0 = __builtin_amdgcn_mfma_i32_16x16x64_i8(R00, Bf, ar0, 0, 0, 0);
          ar1 = __builtin_amdgcn_mfma_i32_16x16x64_i8(R10, Bf, ar1, 0, 0, 0);
          ah0 = __builtin_amdgcn_mfma_i32_16x16x64_i8(H00, Bf, ah0, 0, 0, 0);
          ah1 = __builtin_amdgcn_mfma_i32_16x16x64_i8(H10, Bf, ah1, 0, 0, 0);
          Bf = *(const i32x4*)(hb + bc * 256 + 1 * 64 + hi * 16);
          az0 = __builtin_amdgcn_mfma_i32_16x16x64_i8(Z01, Bf, az0, 0, 0, 0);
          az1 = __builtin_amdgcn_mfma_i32_16x16x64_i8(Z11, Bf, az1, 0, 0, 0);
          ar0 = __builtin_amdgcn_mfma_i32_16x16x64_i8(R01, Bf, ar0, 0, 0, 0);
          ar1 = __builtin_amdgcn_mfma_i32_16x16x64_i8(R11, Bf, ar1, 0, 0, 0);
          ah0 = __builtin_amdgcn_mfma_i32_16x16x64_i8(H01, Bf, ah0, 0, 0, 0);
          ah1 = __builtin_amdgcn_mfma_i32_16x16x64_i8(H11, Bf, ah1, 0, 0, 0);
          Bf = *(const i32x4*)(hb + bc * 256 + 2 * 64 + hi * 16);
          az0 = __builtin_amdgcn_mfma_i32_16x16x64_i8(Z02, Bf, az0, 0, 0, 0);
          az1 = __builtin_amdgcn_mfma_i32_16x16x64_i8(Z12, Bf, az1, 0, 0, 0);
          ar0 = __builtin_amdgcn_mfma_i32_16x16x64_i8(R02, Bf, ar0, 0, 0, 0);
          ar1 = __builtin_amdgcn_mfma_i32_16x16x64_i8(R12, Bf, ar1, 0, 0, 0);
          ah0 = __builtin_amdgcn_mfma_i32_16x16x64_i8(H02, Bf, ah0, 0, 0, 0);
          ah1 = __builtin_amdgcn_mfma_i32_16x16x64_i8(H12, Bf, ah1, 0, 0, 0);
          Bf = *(const i32x4*)(hb + bc * 256 + 3 * 64 + hi * 16);
          az0 = __builtin_amdgcn_mfma_i32_16x16x64_i8(Z03, Bf, az0, 0, 0, 0);
          az1 = __builtin_amdgcn_mfma_i32_16x16x64_i8(Z13, Bf, az1, 0, 0, 0);
          ar0 = __builtin_amdgcn_mfma_i32_16x16x64_i8(R03, Bf, ar0, 0, 0, 0);
          ar1 = __builtin_amdgcn_mfma_i32_16x16x64_i8(R13, Bf, ar1, 0, 0, 0);
          ah0 = __builtin_amdgcn_mfma_i32_16x16x64_i8(H03, Bf, ah0, 0, 0, 0);
          ah1 = __builtin_amdgcn_mfma_i32_16x16x64_i8(H13, Bf, ah1, 0, 0, 0);
        }

#define SEL4(a) ((qq & 2) ? ((qq & 1) ? (a)[3] : (a)[2]) : ((qq & 1) ? (a)[1] : (a)[0]))
        int azi = s2 ? SEL4(az1) : SEL4(az0);
        int ari = s2 ? SEL4(ar1) : SEL4(ar0);
        int ahi = s2 ? SEL4(ah1) : SEL4(ah0);
#undef SEL4
        float z  = rcpf(1.f + __expf(-fmaf((float)azi, dq, xzf)));
        float r  = rcpf(1.f + __expf(-fmaf((float)ari, dq, xrf)));
        float ph = fmaf((float)ahi, dq, xhf);
        float y  = fmaf(r, ph - h, h);
        float th = fmaf(2.f, rcpf(1.f + __expf(-2.f * y)), -1.f);
        h = fmaf(z, h - th, th);

        outp[(size_t)t * U_] = h;
        int q8 = __float2int_rn(h * 127.f);
        U.s.Hq[(t & 1) ^ 1][hwa] = (char)q8;
        __syncthreads();
      }

      hg[(size_t)(g * 2 + bc) * 256 + u] = h;
    } else {
      // parked waves: match barrier count (1 pre-loop + TC in-loop)
      for (int t = 0; t <= TC; ++t) __syncthreads();
    }
    return;
  }
  bid -= nScan;

  // ================= GEMM =================
  if (bid < nGemm) {
    const int tile = bid;
    const int mt = tile / 6, nt = tile % 6;
    const int w = tid >> 6, l = tid & 63;
    const int wm = (w & 3) * 32, wn = (w >> 2) * 32;
    const char* Ab = (const char*)xhc + (size_t)mt * 128 * 512;
    const char* Bb = (const char*)kT  + (size_t)nt * 128 * 512;
    f32x4 acc[2][2] = {};

    const bool isA = tid < 512;
    const int cc = isA ? tid : tid - 512;
    const int srow = cc >> 2, sgq = cc & 3;
    const int sgs = sgq ^ ((srow >> 1) & 3);
    const char* sb = isA ? Ab : Bb;
    char* ldsb = (char*)(isA ? U.g.As : U.g.Bs) + cc * 16;

    for (int kt = 0; kt < 8; ++kt) {
      __builtin_amdgcn_global_load_lds(
        (gptr_t)(sb + (size_t)srow * 512 + kt * 64 + sgs * 16),
        (lptr_t)ldsb, 16, 0, 0);
      __syncthreads();

      half8_t av[2], bv[2];
      #pragma unroll
      for (int mi = 0; mi < 2; ++mi) {
        int row = wm + mi * 16 + (l & 15);
        int off = row * 64 + (((l >> 4) ^ ((row >> 1) & 3)) << 4);
        av[mi] = *(const half8_t*)((const char*)U.g.As + off);
      }
      #pragma unroll
      for (int ni = 0; ni < 2; ++ni) {
        int row = wn + ni * 16 + (l & 15);
        int off = row * 64 + (((l >> 4) ^ ((row >> 1) & 3)) << 4);
        bv[ni] = *(const half8_t*)((const char*)U.g.Bs + off);
      }
      #pragma unroll
      for (int mi = 0; mi < 2; ++mi)
        #pragma unroll
        for (int ni = 0; ni < 2; ++ni)
          acc[mi][ni] = __builtin_amdgcn_mfma_f32_16x16x32_f16(av[mi], bv[ni], acc[mi][ni], 0, 0, 0);
      __syncthreads();
    }

    // epilogue: scatter to scan page layout with bias add
    #pragma unroll
    for (int mi = 0; mi < 2; ++mi) {
      #pragma unroll
      for (int ni = 0; ni < 2; ++ni) {
        int c = nt * 128 + wn + ni * 16 + (l & 15);
        int cgate = c >> 8, u2 = c & 255;
        int wv = u2 >> 5, s2 = (u2 >> 4) & 1, hi2 = (u2 >> 2) & 3, q2 = u2 & 3;
        int stidBase = wv * 64 + hi2 * 16 + (((s2 << 2) | q2) << 1);
        float bc = bias[c];
        #pragma unroll
        for (int q = 0; q < 4; ++q) {
          int arow = mt * 128 + wm + mi * 16 + ((l >> 4) * 4 + q);
          int b = arow >> 9, tloc = arow & 511;
          int gg = b >> 1, bcl = b & 1;
          int stid = stidBase + bcl;
          size_t pageH = (size_t)(gg * 512 + tloc) * 1536;  // f16 units
          size_t dst = (cgate < 2) ? (pageH + (size_t)stid * 2 + cgate)
                                   : (pageH + 1024 + stid);
          xwsG[dst] = (_Float16)(acc[mi][ni][q] + bc);
        }
      }
    }
    return;
  }
  bid -= nGemm;

  // ================= LN (in-place on out) =================
  {
    int rid = bid * 16 + (tid >> 6);
    int l = tid & 63;
    int b = rid >> 9, tl = rid & 511;
    float* p = out + ((size_t)b * T_ + lnT0 + tl) * U_ + l * 4;
    f32x4 v = *(const f32x4*)p;
    float s  = (v[0] + v[1]) + (v[2] + v[3]);
    float s2 = (v[0]*v[0] + v[1]*v[1]) + (v[2]*v[2] + v[3]*v[3]);
    #pragma unroll
    for (int off = 1; off <= 32; off <<= 1) {
      s  += __shfl_xor(s, off);
      s2 += __shfl_xor(s2, off);
    }
    float mu = s * (1.f / 256.f);
    float var = s2 * (1.f / 256.f) - mu * mu;
    float rs = rsqrtf(var + 1e-6f);
    f32x4 gm = *(const f32x4*)(gamma + l * 4);
    f32x4 bt = *(const f32x4*)(beta + l * 4);
    f32x4 o;
    o[0] = (v[0] - mu) * rs * gm[0] + bt[0];
    o[1] = (v[1] - mu) * rs * gm[1] + bt[1];
    o[2] = (v[2] - mu) * rs * gm[2] + bt[2];
    o[3] = (v[3] - mu) * rs * gm[3] + bt[3];
    *(f32x4*)p = o;
  }
}

// ---------------- launcher ----------------
extern "C" void kernel_launch(void* const* d_in, const int* in_sizes, int n_in,
                              void* d_out, int out_size, void* d_ws, size_t ws_size,
                              hipStream_t stream) {
  const float* x     = (const float*)d_in[0];
  const float* kern  = (const float*)d_in[1];
  const float* rec   = (const float*)d_in[2];
  const float* bias  = (const float*)d_in[3];
  const float* gamma = (const float*)d_in[4];
  const float* beta  = (const float*)d_in[5];
  float* out = (float*)d_out;
  char* ws = (char*)d_ws;

  const size_t XWS = 50331648;  // 32*512*1536*2
  const bool pipe = (ws_size >= 118096000ull);

  _Float16* xwsA = (_Float16*)ws;
  _Float16* xwsB = pipe ? (_Float16*)(ws + XWS) : xwsA;
  size_t o = pipe ? 2 * XWS : XWS;
  _Float16* xhc = (_Float16*)(ws + o);           o += 16777216;
  _Float16* kT  = (_Float16*)(ws + o);           o += 393216;
  char*     rq  = (char*)    (ws + o);           o += 196608;
  unsigned* sc  = (unsigned*)(ws + o);           o += 128;
  float*    hg  = (float*)   (ws + o);

  init_scale<<<1, 64, 0, stream>>>(sc);
  absmax_rec<<<192, 256, 0, stream>>>(rec, sc);
  conv_T<<<768, 256, 0, stream>>>(kern, kT);
  conv_rec_i8<<<768, 256, 0, stream>>>(rec, sc, rq);

  if (pipe) {
    conv_x_chunk<<<4096, 256, 0, stream>>>(x, xhc, 0);
    mega<<<GB_GEMM, 1024, 0, stream>>>(rq, xwsA, sc, out, hg, 0,
                                       xhc, kT, bias, xwsA, gamma, beta, 0,
                                       0, GB_GEMM);
    conv_x_chunk<<<4096, 256, 0, stream>>>(x, xhc, TC);
    mega<<<GB_SCAN + GB_GEMM, 1024, 0, stream>>>(rq, xwsA, sc, out, hg, 0,
                                       xhc, kT, bias, xwsB, gamma, beta, 0,
                                       GB_SCAN, GB_GEMM);
    conv_x_chunk<<<4096, 256, 0, stream>>>(x, xhc, 2 * TC);
    mega<<<GB_SCAN + GB_GEMM + GB_LN, 1024, 0, stream>>>(rq, xwsB, sc, out, hg, TC,
                                       xhc, kT, bias, xwsA, gamma, beta, 0,
                                       GB_SCAN, GB_GEMM);
    conv_x_chunk<<<4096, 256, 0, stream>>>(x, xhc, 3 * TC);
    mega<<<GB_SCAN + GB_GEMM + GB_LN, 1024, 0, stream>>>(rq, xwsA, sc, out, hg, 2 * TC,
                                       xhc, kT, bias, xwsB, gamma, beta, TC,
                                       GB_SCAN, GB_GEMM);
    mega<<<GB_SCAN + GB_LN, 1024, 0, stream>>>(rq, xwsB, sc, out, hg, 3 * TC,
                                       xhc, kT, bias, xwsA, gamma, beta, 2 * TC,
                                       GB_SCAN, 0);
    mega<<<GB_LN, 1024, 0, stream>>>(rq, xwsA, sc, out, hg, 0,
                                       xhc, kT, bias, xwsA, gamma, beta, 3 * TC,
                                       0, 0);
  } else {
    for (int c = 0; c < NCHUNK; ++c) {
      int t0 = c * TC;
      conv_x_chunk<<<4096, 256, 0, stream>>>(x, xhc, t0);
      mega<<<GB_GEMM, 1024, 0, stream>>>(rq, xwsA, sc, out, hg, t0,
                                         xhc, kT, bias, xwsA, gamma, beta, t0,
                                         0, GB_GEMM);
      mega<<<GB_SCAN, 1024, 0, stream>>>(rq, xwsA, sc, out, hg, t0,
                                         xhc, kT, bias, xwsA, gamma, beta, t0,
                                         GB_SCAN, 0);
      mega<<<GB_LN, 1024, 0, stream>>>(rq, xwsA, sc, out, hg, t0,
                                       xhc, kT, bias, xwsA, gamma, beta, t0,
                                       0, 0);
    }
  }
}

// Round 11
// 1452.758 us; speedup vs baseline: 3.1366x; 3.1366x over previous
//
#include <hip/hip_runtime.h>
#include <hip/hip_bf16.h>
#include <hip/hip_fp16.h>

using half2_t = __attribute__((ext_vector_type(2))) _Float16;
using half8_t = __attribute__((ext_vector_type(8))) _Float16;
using f32x4   = __attribute__((ext_vector_type(4))) float;
using i32x4   = __attribute__((ext_vector_type(4))) int;

#define B_   64
#define T_   2048
#define D_   256
#define U_   256
#define NG   768
#define TC   512
#define NCHUNK (T_/TC)
#define GB_SCAN 16     // scan blocks (4 batches each)
#define GB_GEMM 1536
#define GB_LN   2048

typedef const __attribute__((address_space(1))) void* gptr_t;
typedef __attribute__((address_space(3))) void* lptr_t;

__device__ __forceinline__ float rcpf(float x) { return __builtin_amdgcn_rcpf(x); }

// ---------------- prep kernels ----------------

__global__ void conv_x_chunk(const float* __restrict__ x, _Float16* __restrict__ xh, int t0) {
  size_t idx = ((size_t)blockIdx.x * 256 + threadIdx.x) * 8;
  int b   = (int)(idx >> 17);
  int rem = (int)(idx & 131071);
  const float4* p = (const float4*)(x + ((size_t)(b * T_ + t0)) * D_ + rem);
  float4 v0 = p[0], v1 = p[1];
  half8_t o;
  o[0] = (_Float16)v0.x; o[1] = (_Float16)v0.y; o[2] = (_Float16)v0.z; o[3] = (_Float16)v0.w;
  o[4] = (_Float16)v1.x; o[5] = (_Float16)v1.y; o[6] = (_Float16)v1.z; o[7] = (_Float16)v1.w;
  *(half8_t*)(xh + idx) = o;
}

__global__ void conv_T(const float* __restrict__ src, _Float16* __restrict__ dst) {
  int idx = blockIdx.x * 256 + threadIdx.x;
  int d = idx / NG;
  int j = idx - d * NG;
  dst[j * 256 + d] = (_Float16)src[idx];
}

__global__ void init_scale(unsigned* s) { if (threadIdx.x == 0) *s = 0u; }

__global__ void absmax_rec(const float* __restrict__ rec, unsigned* __restrict__ s) {
  int i = (blockIdx.x * 256 + threadIdx.x) * 4;
  float4 v = *(const float4*)(rec + i);
  float m = fmaxf(fmaxf(fabsf(v.x), fabsf(v.y)), fmaxf(fabsf(v.z), fabsf(v.w)));
  #pragma unroll
  for (int off = 32; off >= 1; off >>= 1) m = fmaxf(m, __shfl_xor(m, off));
  __shared__ float sm[4];
  int l = threadIdx.x & 63, wv = threadIdx.x >> 6;
  if (l == 0) sm[wv] = m;
  __syncthreads();
  if (threadIdx.x == 0) {
    m = fmaxf(fmaxf(sm[0], sm[1]), fmaxf(sm[2], sm[3]));
    atomicMax(s, __float_as_uint(m));
  }
}

// rec [256][768] f32 -> i8 A-fragment layout [48 mt][4 ks][64 lane][16B]
__global__ void conv_rec_i8(const float* __restrict__ rec, const unsigned* __restrict__ sc,
                            char* __restrict__ dst) {
  int idx = blockIdx.x * 256 + threadIdx.x;
  int j = idx & 15, l = (idx >> 4) & 63, sl = idx >> 10;
  int mt = sl >> 2, ks = sl & 3, bi = l & 15, hi = l >> 4;
  float am = __uint_as_float(*sc) + 1e-30f;
  float s = 127.f / am;
  float v = rec[(size_t)(ks * 64 + hi * 16 + j) * NG + mt * 16 + bi] * s;
  int q = __float2int_rn(v);
  q = q > 127 ? 127 : (q < -127 ? -127 : q);
  dst[idx] = (char)q;
}

// ---------------- mega kernel: [scan | gemm | ln] by blockIdx range ----------------
// xws page layout per (g,t): 3072 f16 = 6144 B: [0,4096)B zr pairs (lane*4B), [4096,6144)B h (lane*2B)

__global__ __launch_bounds__(1024) void mega(
    const char* __restrict__ rq,        // [48][4][64][16] i8
    const _Float16* __restrict__ xwsS,
    const unsigned* __restrict__ sc,
    float* __restrict__ out,
    float* __restrict__ hg,
    int scanT0,
    const _Float16* __restrict__ xhc,
    const _Float16* __restrict__ kT,
    const float* __restrict__ bias,
    _Float16* __restrict__ xwsG,
    const float* __restrict__ gamma,
    const float* __restrict__ beta,
    int lnT0,
    int nScan, int nGemm)
{
  __shared__ union UU {
    struct { alignas(16) char Hq[2][1024]; } s;
    struct { alignas(16) _Float16 As[128 * 32]; alignas(16) _Float16 Bs[128 * 32]; } g;
  } U;

  int bid = blockIdx.x;
  const int tid = threadIdx.x;

  // ================= SCAN =================
  if (bid < nScan) {
    const int g = bid;
    const int w = tid >> 6, l = tid & 63, bi = l & 15, hi = l >> 4;
    const int bc = bi & 3, qq = bi >> 2;
    const int u = w * 16 + hi * 4 + qq;

    // A-frags: 12 named i32x4 (48 VGPR)
    const i32x4* rp = (const i32x4*)rq;
#define FR(mt, ks) rp[((mt) * 4 + (ks)) * 64 + l]
    i32x4 Az0 = FR(w, 0),      Az1 = FR(w, 1),      Az2 = FR(w, 2),      Az3 = FR(w, 3);
    i32x4 Ar0 = FR(16 + w, 0), Ar1 = FR(16 + w, 1), Ar2 = FR(16 + w, 2), Ar3 = FR(16 + w, 3);
    i32x4 Ah0 = FR(32 + w, 0), Ah1 = FR(32 + w, 1), Ah2 = FR(32 + w, 2), Ah3 = FR(32 + w, 3);
#undef FR
    asm volatile("" : "+v"(Az0), "+v"(Az1), "+v"(Az2), "+v"(Az3),
                      "+v"(Ar0), "+v"(Ar1), "+v"(Ar2), "+v"(Ar3),
                      "+v"(Ah0), "+v"(Ah1), "+v"(Ah2), "+v"(Ah3));

    const float dq = (__uint_as_float(*sc) + 1e-30f) / (127.f * 127.f);

    float h = (scanT0 == 0) ? 0.f : hg[(size_t)(g * 4 + bc) * 256 + u];

    const int hwa = bc * 256 + ((w ^ bc) << 4) + hi * 4 + qq;
    { int q8 = __float2int_rn(h * 127.f); U.s.Hq[0][hwa] = (char)q8; }

    // strength-reduced pointers: advance by one 6144B page per step
    const char* xpz = (const char*)xwsS + (size_t)g * TC * 6144 + tid * 4;
    const char* xph = xpz - tid * 4 + 4096 + tid * 2;
    float* outp = out + ((size_t)(g * 4 + bc) * T_ + scanT0) * U_ + u;

    unsigned nzr = *(const unsigned*)xpz;
    _Float16 nh2 = *(const _Float16*)xph;
    int hrd = 0;   // read-buffer byte offset, toggled by ^1024
    __syncthreads();

    #pragma unroll 1
    for (int t = 0; t < TC; ++t) {
      half2_t zrp = __builtin_bit_cast(half2_t, nzr);
      float xzf = (float)zrp[0], xrf = (float)zrp[1], xhf = (float)nh2;
      // unconditional prefetch of next page (last iter over-reads into adjacent ws)
      xpz += 6144; xph += 6144;
      nzr = *(const unsigned*)xpz;
      nh2 = *(const _Float16*)xph;

      const char* hb = &U.s.Hq[0][0] + hrd;
      i32x4 az = {}, ar = {}, ah = {};
#define BADDR(ks) (bc * 256 + ((((ks) * 4 + hi) ^ bc) << 4))
      { i32x4 Bf;
        Bf = *(const i32x4*)(hb + BADDR(0));
        az = __builtin_amdgcn_mfma_i32_16x16x64_i8(Az0, Bf, az, 0, 0, 0);
        ar = __builtin_amdgcn_mfma_i32_16x16x64_i8(Ar0, Bf, ar, 0, 0, 0);
        ah = __builtin_amdgcn_mfma_i32_16x16x64_i8(Ah0, Bf, ah, 0, 0, 0);
        Bf = *(const i32x4*)(hb + BADDR(1));
        az = __builtin_amdgcn_mfma_i32_16x16x64_i8(Az1, Bf, az, 0, 0, 0);
        ar = __builtin_amdgcn_mfma_i32_16x16x64_i8(Ar1, Bf, ar, 0, 0, 0);
        ah = __builtin_amdgcn_mfma_i32_16x16x64_i8(Ah1, Bf, ah, 0, 0, 0);
        Bf = *(const i32x4*)(hb + BADDR(2));
        az = __builtin_amdgcn_mfma_i32_16x16x64_i8(Az2, Bf, az, 0, 0, 0);
        ar = __builtin_amdgcn_mfma_i32_16x16x64_i8(Ar2, Bf, ar, 0, 0, 0);
        ah = __builtin_amdgcn_mfma_i32_16x16x64_i8(Ah2, Bf, ah, 0, 0, 0);
        Bf = *(const i32x4*)(hb + BADDR(3));
        az = __builtin_amdgcn_mfma_i32_16x16x64_i8(Az3, Bf, az, 0, 0, 0);
        ar = __builtin_amdgcn_mfma_i32_16x16x64_i8(Ar3, Bf, ar, 0, 0, 0);
        ah = __builtin_amdgcn_mfma_i32_16x16x64_i8(Ah3, Bf, ah, 0, 0, 0);
      }
#undef BADDR

#define SEL4(a) ((qq & 2) ? ((qq & 1) ? (a)[3] : (a)[2]) : ((qq & 1) ? (a)[1] : (a)[0]))
      float pz = (float)SEL4(az) * dq + xzf;
      float pr = (float)SEL4(ar) * dq + xrf;
      float ph = (float)SEL4(ah) * dq + xhf;
#undef SEL4
      float z  = rcpf(1.f + __expf(-pz));
      float r  = rcpf(1.f + __expf(-pr));
      float y  = r * (ph - h) + h;
      float th = 2.f * rcpf(1.f + __expf(-2.f * y)) - 1.f;
      h = z * (h - th) + th;

      *outp = h;
      outp += U_;
      int q8 = __float2int_rn(h * 127.f);
      U.s.Hq[0][(hrd ^ 1024) + hwa] = (char)q8;
      hrd ^= 1024;
      __syncthreads();
    }

    hg[(size_t)(g * 4 + bc) * 256 + u] = h;
    return;
  }
  bid -= nScan;

  // ================= GEMM =================
  if (bid < nGemm) {
    const int tile = bid;
    const int mt = tile / 6, nt = tile % 6;
    const int w = tid >> 6, l = tid & 63;
    const int wm = (w & 3) * 32, wn = (w >> 2) * 32;
    const char* Ab = (const char*)xhc + (size_t)mt * 128 * 512;
    const char* Bb = (const char*)kT  + (size_t)nt * 128 * 512;
    f32x4 acc[2][2] = {};

    const bool isA = tid < 512;
    const int cc = isA ? tid : tid - 512;
    const int srow = cc >> 2, sgq = cc & 3;
    const int sgs = sgq ^ ((srow >> 1) & 3);
    const char* sb = isA ? Ab : Bb;
    char* ldsb = (char*)(isA ? U.g.As : U.g.Bs) + cc * 16;

    for (int kt = 0; kt < 8; ++kt) {
      __builtin_amdgcn_global_load_lds(
        (gptr_t)(sb + (size_t)srow * 512 + kt * 64 + sgs * 16),
        (lptr_t)ldsb, 16, 0, 0);
      __syncthreads();

      half8_t av[2], bv[2];
      #pragma unroll
      for (int mi = 0; mi < 2; ++mi) {
        int row = wm + mi * 16 + (l & 15);
        int off = row * 64 + (((l >> 4) ^ ((row >> 1) & 3)) << 4);
        av[mi] = *(const half8_t*)((const char*)U.g.As + off);
      }
      #pragma unroll
      for (int ni = 0; ni < 2; ++ni) {
        int row = wn + ni * 16 + (l & 15);
        int off = row * 64 + (((l >> 4) ^ ((row >> 1) & 3)) << 4);
        bv[ni] = *(const half8_t*)((const char*)U.g.Bs + off);
      }
      #pragma unroll
      for (int mi = 0; mi < 2; ++mi)
        #pragma unroll
        for (int ni = 0; ni < 2; ++ni)
          acc[mi][ni] = __builtin_amdgcn_mfma_f32_16x16x32_f16(av[mi], bv[ni], acc[mi][ni], 0, 0, 0);
      __syncthreads();
    }

    // epilogue: scatter to scan page layout with bias add
    #pragma unroll
    for (int mi = 0; mi < 2; ++mi) {
      #pragma unroll
      for (int ni = 0; ni < 2; ++ni) {
        int c = nt * 128 + wn + ni * 16 + (l & 15);
        int cgate = c >> 8, uu = c & 255;
        int wv = uu >> 4, hq = (uu >> 2) & 3, qv = uu & 3;
        int lane_tid = wv * 64 + (qv << 2) + (hq << 4);
        float bc = bias[c];
        #pragma unroll
        for (int q = 0; q < 4; ++q) {
          int arow = mt * 128 + wm + mi * 16 + ((l >> 4) * 4 + q);
          int b = arow >> 9, tloc = arow & 511;
          int g = b >> 2, bidx = b & 3;
          int lane = lane_tid + bidx;
          size_t page = (size_t)(g * 512 + tloc) * 3072;
          size_t dst = (cgate < 2) ? (page + (size_t)lane * 2 + cgate)
                                   : (page + 2048 + lane);
          xwsG[dst] = (_Float16)(acc[mi][ni][q] + bc);
        }
      }
    }
    return;
  }
  bid -= nGemm;

  // ================= LN (in-place on out) =================
  {
    int rid = bid * 16 + (tid >> 6);
    int l = tid & 63;
    int b = rid >> 9, tl = rid & 511;
    float* p = out + ((size_t)b * T_ + lnT0 + tl) * U_ + l * 4;
    f32x4 v = *(const f32x4*)p;
    float s  = (v[0] + v[1]) + (v[2] + v[3]);
    float s2 = (v[0]*v[0] + v[1]*v[1]) + (v[2]*v[2] + v[3]*v[3]);
    #pragma unroll
    for (int off = 1; off <= 32; off <<= 1) {
      s  += __shfl_xor(s, off);
      s2 += __shfl_xor(s2, off);
    }
    float mu = s * (1.f / 256.f);
    float var = s2 * (1.f / 256.f) - mu * mu;
    float rs = rsqrtf(var + 1e-6f);
    f32x4 gm = *(const f32x4*)(gamma + l * 4);
    f32x4 bt = *(const f32x4*)(beta + l * 4);
    f32x4 o;
    o[0] = (v[0] - mu) * rs * gm[0] + bt[0];
    o[1] = (v[1] - mu) * rs * gm[1] + bt[1];
    o[2] = (v[2] - mu) * rs * gm[2] + bt[2];
    o[3] = (v[3] - mu) * rs * gm[3] + bt[3];
    *(f32x4*)p = o;
  }
}

// ---------------- launcher ----------------
extern "C" void kernel_launch(void* const* d_in, const int* in_sizes, int n_in,
                              void* d_out, int out_size, void* d_ws, size_t ws_size,
                              hipStream_t stream) {
  const float* x     = (const float*)d_in[0];
  const float* kern  = (const float*)d_in[1];
  const float* rec   = (const float*)d_in[2];
  const float* bias  = (const float*)d_in[3];
  const float* gamma = (const float*)d_in[4];
  const float* beta  = (const float*)d_in[5];
  float* out = (float*)d_out;
  char* ws = (char*)d_ws;

  const size_t XWS = 50331648;  // 16*512*3072*2
  const bool pipe = (ws_size >= 118096000ull);

  _Float16* xwsA = (_Float16*)ws;
  _Float16* xwsB = pipe ? (_Float16*)(ws + XWS) : xwsA;
  size_t o = pipe ? 2 * XWS : XWS;
  _Float16* xhc = (_Float16*)(ws + o);           o += 16777216;
  _Float16* kT  = (_Float16*)(ws + o);           o += 393216;
  char*     rq  = (char*)    (ws + o);           o += 196608;
  unsigned* sc  = (unsigned*)(ws + o);           o += 128;
  float*    hg  = (float*)   (ws + o);

  init_scale<<<1, 64, 0, stream>>>(sc);
  absmax_rec<<<192, 256, 0, stream>>>(rec, sc);
  conv_T<<<768, 256, 0, stream>>>(kern, kT);
  conv_rec_i8<<<768, 256, 0, stream>>>(rec, sc, rq);

  if (pipe) {
    conv_x_chunk<<<4096, 256, 0, stream>>>(x, xhc, 0);
    mega<<<GB_GEMM, 1024, 0, stream>>>(rq, xwsA, sc, out, hg, 0,
                                       xhc, kT, bias, xwsA, gamma, beta, 0,
                                       0, GB_GEMM);
    conv_x_chunk<<<4096, 256, 0, stream>>>(x, xhc, TC);
    mega<<<GB_SCAN + GB_GEMM, 1024, 0, stream>>>(rq, xwsA, sc, out, hg, 0,
                                       xhc, kT, bias, xwsB, gamma, beta, 0,
                                       GB_SCAN, GB_GEMM);
    conv_x_chunk<<<4096, 256, 0, stream>>>(x, xhc, 2 * TC);
    mega<<<GB_SCAN + GB_GEMM + GB_LN, 1024, 0, stream>>>(rq, xwsB, sc, out, hg, TC,
                                       xhc, kT, bias, xwsA, gamma, beta, 0,
                                       GB_SCAN, GB_GEMM);
    conv_x_chunk<<<4096, 256, 0, stream>>>(x, xhc, 3 * TC);
    mega<<<GB_SCAN + GB_GEMM + GB_LN, 1024, 0, stream>>>(rq, xwsA, sc, out, hg, 2 * TC,
                                       xhc, kT, bias, xwsB, gamma, beta, TC,
                                       GB_SCAN, GB_GEMM);
    mega<<<GB_SCAN + GB_LN, 1024, 0, stream>>>(rq, xwsB, sc, out, hg, 3 * TC,
                                       xhc, kT, bias, xwsA, gamma, beta, 2 * TC,
                                       GB_SCAN, 0);
    mega<<<GB_LN, 1024, 0, stream>>>(rq, xwsA, sc, out, hg, 0,
                                       xhc, kT, bias, xwsA, gamma, beta, 3 * TC,
                                       0, 0);
  } else {
    for (int c = 0; c < NCHUNK; ++c) {
      int t0 = c * TC;
      conv_x_chunk<<<4096, 256, 0, stream>>>(x, xhc, t0);
      mega<<<GB_GEMM, 1024, 0, stream>>>(rq, xwsA, sc, out, hg, t0,
                                         xhc, kT, bias, xwsA, gamma, beta, t0,
                                         0, GB_GEMM);
      mega<<<GB_SCAN, 1024, 0, stream>>>(rq, xwsA, sc, out, hg, t0,
                                         xhc, kT, bias, xwsA, gamma, beta, t0,
                                         GB_SCAN, 0);
      mega<<<GB_LN, 1024, 0, stream>>>(rq, xwsA, sc, out, hg, t0,
                                       xhc, kT, bias, xwsA, gamma, beta, t0,
                                       0, 0);
    }
  }
}